// Round 5
// baseline (540.051 us; speedup 1.0000x reference)
//
#include <hip/hip_runtime.h>

typedef unsigned short u16;
typedef unsigned int u32;
typedef __bf16 bf16x8 __attribute__((ext_vector_type(8)));
typedef float f32x4 __attribute__((ext_vector_type(4)));

#define DEVI __device__ __forceinline__

#define BB 16
#define NN 577
#define CC 1024
#define HH 16
#define DD 64
#define BN 9232     // B*N rows
#define PIX 576     // 24*24
#define WW 24
#define CHN 256
#define VROW 584    // padded v^T row length (16B-aligned rows)
#define PSZ (9216 * 256)  // one conv1 partial (elements)

DEVI u16 f2b(float f) {
  u32 u = __builtin_bit_cast(u32, f);
  u32 r = 0x7FFFu + ((u >> 16) & 1u);
  return (u16)((u + r) >> 16);
}

DEVI float b2f(u16 h) { return __builtin_bit_cast(float, (u32)h << 16); }

DEVI bf16x8 ldfrag(const u16* p) {
  uint4 u = *(const uint4*)p;
  return __builtin_bit_cast(bf16x8, u);
}

DEVI f32x4 mfma16(bf16x8 a, bf16x8 b, f32x4 c) {
  return __builtin_amdgcn_mfma_f32_16x16x32_bf16(a, b, c, 0, 0, 0);
}

DEVI void gld_lds16(const u16* g, u16* l) {
  __builtin_amdgcn_global_load_lds((const __attribute__((address_space(1))) void*)g,
                                   (__attribute__((address_space(3))) void*)l, 16, 0, 0);
}

DEVI float gelu_tanh(float v) {
  const float x3 = v * v * v;
  const float t = __expf(1.5957691216057308f * (v + 0.044715f * x3));
  const float th = (t - 1.f) / (t + 1.f);
  return 0.5f * v * (1.f + th);
}

// ---------------- prep: weight bf16 conversion + conv-weight permute + zero page ----
__global__ __launch_bounds__(256) void prep_kernel(
    const float* __restrict__ in_w, const float* __restrict__ out_w,
    const float* __restrict__ c1w, const float* __restrict__ c2w,
    u16* __restrict__ wqkv, u16* __restrict__ wout,
    u16* __restrict__ w1t, u16* __restrict__ w2t, u16* __restrict__ zpad) {
  const int i0 = blockIdx.x * 256 + threadIdx.x;
  const int stride = gridDim.x * 256;
  for (int i = i0; i < 3072 * 1024; i += stride) wqkv[i] = f2b(in_w[i]);
  for (int i = i0; i < 1024 * 1024; i += stride) wout[i] = f2b(out_w[i]);
  for (int i = i0; i < 256 * 9216; i += stride) {
    int oc = i / 9216, rem = i - oc * 9216, tap = rem >> 10, c = rem & 1023;
    w1t[i] = f2b(c1w[(size_t)oc * 9216 + c * 9 + tap]);
  }
  for (int i = i0; i < 1024 * 2304; i += stride) {
    int oc = i / 2304, rem = i - oc * 2304, tap = rem >> 8, c = rem & 255;
    w2t[i] = f2b(c2w[(size_t)oc * 2304 + c * 9 + tap]);
  }
  if (i0 < 128) zpad[i0] = 0;
}

// ---------------- LayerNorm (row of 1024), writes bf16; MODE1 also writes cls rows to out
template <int MODE>
__global__ __launch_bounds__(256) void ln_kernel(
    const float* __restrict__ xin, const float* __restrict__ gam,
    const float* __restrict__ bet, u16* __restrict__ yout, float* __restrict__ oextra) {
  __shared__ float sh[8];
  const int row = blockIdx.x;
  const int tid = threadIdx.x;
  const float4 v = ((const float4*)(xin + (size_t)row * CC))[tid];
  float s = v.x + v.y + v.z + v.w;
  float qq = v.x * v.x + v.y * v.y + v.z * v.z + v.w * v.w;
#pragma unroll
  for (int off = 32; off > 0; off >>= 1) {
    s += __shfl_down(s, off);
    qq += __shfl_down(qq, off);
  }
  if ((tid & 63) == 0) { sh[tid >> 6] = s; sh[4 + (tid >> 6)] = qq; }
  __syncthreads();
  s = sh[0] + sh[1] + sh[2] + sh[3];
  qq = sh[4] + sh[5] + sh[6] + sh[7];
  const float mu = s * (1.f / 1024.f);
  const float rstd = rsqrtf(qq * (1.f / 1024.f) - mu * mu + 1e-5f);
  const float4 g4 = ((const float4*)gam)[tid];
  const float4 b4 = ((const float4*)bet)[tid];
  const float o0 = (v.x - mu) * rstd * g4.x + b4.x;
  const float o1 = (v.y - mu) * rstd * g4.y + b4.y;
  const float o2 = (v.z - mu) * rstd * g4.z + b4.z;
  const float o3 = (v.w - mu) * rstd * g4.w + b4.w;
  ushort4 st = make_ushort4(f2b(o0), f2b(o1), f2b(o2), f2b(o3));
  *(ushort4*)(yout + (size_t)row * CC + tid * 4) = st;
  if constexpr (MODE == 1) {
    if (row % NN == NN - 1) {
      float4 ov = make_float4(v.x + o0, v.y + o1, v.z + o2, v.w + o3);
      ((float4*)(oextra + (size_t)row * CC))[tid] = ov;
    }
  }
}

// ---------------- 128x128 MFMA GEMM, BK=32, depth-3 pipeline (4 LDS bufs) ----------
// grid: (n_tiles, m_tiles[, z]) so bid%8 = n_tile%8 -> per-XCD B-panel residency
// MODE 0: QKV   -> q(pre-scaled),k (b,h,n,d) + v^T (b,h,d,n) via LDS transpose
// MODE 1: PROJ  -> x2 = acc + bias + res  (f32)
// MODE 3: CONV2 -> out = acc + bias + x2 (f32, row remap)
// MODE 4: CONV1 split-K by tap -> bf16 partial
struct GArgs {
  const u16* A; const u16* Bm; const float* bias; const float* res;
  float* outF; u16* outH; u16* outQ; u16* outK; u16* outV; const u16* zpad;
  int M, K;
};

template <int MODE>
__global__ __launch_bounds__(256) void gemm_kernel(GArgs ag) {
  __shared__ u16 SH[32768];  // 64 KB: A bufs [0,16384), B bufs [16384,32768)
  const int tid = threadIdx.x;
  const int w = tid >> 6, l = tid & 63;
  const int wr = w >> 1, wc = w & 1;
  const int lr = l & 15, lg = l >> 4;
  const int m0 = blockIdx.y * 128, n0 = blockIdx.x * 128;
  const int tapz = (MODE == 4) ? blockIdx.z : 0;
  const int rA = w * 16 + (l >> 2);
  const int cbs = ((l & 3) ^ ((l >> 3) & 3)) * 8;  // source-side XOR (LDS stays linear)

  auto stage = [&](int buf, int kt) {
    const int k0 = kt * 32;
    u16* Ald = SH + buf * 4096;
    u16* Bld = SH + 16384 + buf * 4096;
#pragma unroll
    for (int c = 0; c < 2; ++c) {
      const int r = c * 64 + rA;
      const u16* asrc;
      if constexpr (MODE <= 1) {
        int m = m0 + r;
        m = m < ag.M ? m : ag.M - 1;
        asrc = ag.A + (size_t)m * ag.K + (k0 + cbs);
      } else {
        const int m = m0 + r;
        const int b = m / PIX, p = m - b * PIX;
        const int py = p / WW, px = p - py * WW;
        constexpr int CKc = (MODE == 3) ? 256 : 1024;
        const int tap = (MODE == 4) ? tapz : (k0 / CKc);
        const int c0 = (MODE == 4) ? k0 : (k0 - tap * CKc);
        const int py2 = py + (tap / 3) - 1, px2 = px + (tap % 3) - 1;
        if ((u32)py2 < (u32)WW && (u32)px2 < (u32)WW) {
          if constexpr (MODE == 4)
            asrc = ag.A + ((size_t)(b * NN + py2 * WW + px2) * CC + c0 + cbs);
          else
            asrc = ag.A + ((size_t)(b * PIX + py2 * WW + px2) * CHN + c0 + cbs);
        } else {
          asrc = ag.zpad + cbs;
        }
      }
      gld_lds16(asrc, &Ald[c * 2048 + w * 512]);
      const u16* bsrc;
      if constexpr (MODE == 4)
        bsrc = ag.Bm + (size_t)(n0 + r) * 9216 + (tapz * 1024 + k0 + cbs);
      else
        bsrc = ag.Bm + (size_t)(n0 + r) * ag.K + (k0 + cbs);
      gld_lds16(bsrc, &Bld[c * 2048 + w * 512]);
    }
  };

  f32x4 acc[4][4] = {};
  const int KL = (MODE == 4) ? 1024 : ag.K;
  const int nst = KL >> 5;  // >= 32 for all modes

  stage(0, 0);
  stage(1, 1);
  stage(2, 2);

  const int swz = (lr >> 1) & 3;
  for (int kt = 0; kt < nst; ++kt) {
    asm volatile("s_waitcnt vmcnt(8)" ::: "memory");  // tile kt resident; kt+1,kt+2 in flight
    __builtin_amdgcn_s_barrier();
    if (kt + 3 < nst) stage((kt + 3) & 3, kt + 3);
    const int cur = kt & 3;
    bf16x8 af[4], bfr[4];
#pragma unroll
    for (int i = 0; i < 4; ++i)
      af[i] = ldfrag(&SH[cur * 4096 + (wr * 64 + i * 16 + lr) * 32 + ((lg ^ swz) * 8)]);
#pragma unroll
    for (int i = 0; i < 4; ++i)
      bfr[i] = ldfrag(&SH[16384 + cur * 4096 + (wc * 64 + i * 16 + lr) * 32 + ((lg ^ swz) * 8)]);
    __builtin_amdgcn_s_setprio(1);
#pragma unroll
    for (int mi = 0; mi < 4; ++mi)
#pragma unroll
      for (int ni = 0; ni < 4; ++ni) acc[mi][ni] = mfma16(af[mi], bfr[ni], acc[mi][ni]);
    __builtin_amdgcn_s_setprio(0);
  }

  // ---------------- epilogue ----------------
  if constexpr (MODE == 0) {
    if (n0 >= 2048) {
      // v block: transpose 64x64 wave-quadrants in LDS, write v^T n-contiguous
      __syncthreads();  // all K-loop LDS reads done; SH reusable
      const int G0 = m0 + wr * 64;
      const int b0 = G0 / NN;
      const bool ok = (G0 + 63 < ag.M) && (b0 == (G0 + 63) / NN);
      const int h = (n0 + wc * 64 - 2048) >> 6;
      u16* scr = SH + w * 5120;  // 64 x 80 u16 per wave
      if (ok) {
#pragma unroll
        for (int mi = 0; mi < 4; ++mi) {
#pragma unroll
          for (int ni = 0; ni < 4; ++ni) {
            ushort4 st;
            const float bv = ag.bias[n0 + wc * 64 + ni * 16 + lr];
            st.x = f2b(acc[mi][ni][0] + bv);
            st.y = f2b(acc[mi][ni][1] + bv);
            st.z = f2b(acc[mi][ni][2] + bv);
            st.w = f2b(acc[mi][ni][3] + bv);
            // scr[d][g]: d = ni*16+lr, g = mi*16+lg*4+(0..3)  (stride 80, 8B-aligned)
            *(ushort4*)(scr + (ni * 16 + lr) * 80 + mi * 16 + lg * 4) = st;
          }
        }
        asm volatile("s_waitcnt lgkmcnt(0)" ::: "memory");  // wave-local transpose
        const int nb = G0 - b0 * NN;
        u16* vb = ag.outV + (size_t)((b0 * 16 + h) * 64) * VROW;
#pragma unroll
        for (int pass = 0; pass < 8; ++pass) {
          const int d_ = pass * 8 + (l >> 3);
          const int nn = (l & 7) * 8;
          uint4 vv = *(const uint4*)(scr + d_ * 80 + nn);
          u16* dst = vb + (size_t)d_ * VROW + nb + nn;
          if (!(nb & 1)) {
            ((u32*)dst)[0] = vv.x; ((u32*)dst)[1] = vv.y;
            ((u32*)dst)[2] = vv.z; ((u32*)dst)[3] = vv.w;
          } else {
            u16 tmp[8];
            *(uint4*)tmp = vv;
#pragma unroll
            for (int j = 0; j < 8; ++j) dst[j] = tmp[j];
          }
        }
      } else {
        // tail / batch-crossing quadrant: scalar fallback
#pragma unroll
        for (int mi = 0; mi < 4; ++mi) {
#pragma unroll
          for (int r = 0; r < 4; ++r) {
            const int row = G0 + mi * 16 + lg * 4 + r;
            if (row >= ag.M) continue;
            const int b = row / NN, n = row - b * NN;
#pragma unroll
            for (int ni = 0; ni < 4; ++ni) {
              const int col = n0 + wc * 64 + ni * 16 + lr;
              const int d = col & 63;
              const float v = acc[mi][ni][r] + ag.bias[col];
              ag.outV[((size_t)((b * 16 + h) * 64 + d)) * VROW + n] = f2b(v);
            }
          }
        }
      }
      return;
    }
    // q/k block: coalesced per-element path
#pragma unroll
    for (int mi = 0; mi < 4; ++mi) {
#pragma unroll
      for (int r = 0; r < 4; ++r) {
        const int row = m0 + wr * 64 + mi * 16 + lg * 4 + r;
        if (row >= ag.M) continue;
        const int b = row / NN, n = row - b * NN;
#pragma unroll
        for (int ni = 0; ni < 4; ++ni) {
          const int col = n0 + wc * 64 + ni * 16 + lr;
          const int which = col >> 10, hd = col & 1023, h = hd >> 6, d = hd & 63;
          const float v = acc[mi][ni][r] + ag.bias[col];
          if (which == 0)
            ag.outQ[((size_t)(b * 16 + h) * NN + n) * DD + d] = f2b(v * 0.18033688011112042f);
          else
            ag.outK[((size_t)(b * 16 + h) * NN + n) * DD + d] = f2b(v);
        }
      }
    }
  } else {
#pragma unroll
    for (int mi = 0; mi < 4; ++mi) {
#pragma unroll
      for (int r = 0; r < 4; ++r) {
        const int row = m0 + wr * 64 + mi * 16 + lg * 4 + r;
        if (row >= ag.M) continue;
#pragma unroll
        for (int ni = 0; ni < 4; ++ni) {
          const int col = n0 + wc * 64 + ni * 16 + lr;
          if constexpr (MODE == 4) {
            u16* pb = (tapz < 5) ? ag.outH : ag.outQ;
            const int tl = (tapz < 5) ? tapz : tapz - 5;
            pb[(size_t)tl * PSZ + (size_t)row * CHN + col] = f2b(acc[mi][ni][r]);
          } else {
            const float v = acc[mi][ni][r] + ag.bias[col];
            if constexpr (MODE == 1) {
              const size_t idx = (size_t)row * CC + col;
              ag.outF[idx] = v + ag.res[idx];
            } else {
              const int b = row / PIX, p = row - b * PIX;
              const size_t idx = (size_t)(b * NN + p) * CC + col;
              ag.outF[idx] = v + ag.res[idx];
            }
          }
        }
      }
    }
  }
}

// ---------------- conv1 reduce: f1 = gelu(sum of 9 bf16 partials + bias) -> bf16 ----
__global__ __launch_bounds__(256) void gelu_reduce_kernel(
    const u16* __restrict__ pA, const u16* __restrict__ pB,
    const float* __restrict__ bias, u16* __restrict__ f1) {
  const size_t i4 = ((size_t)blockIdx.x * 256 + threadIdx.x) * 4;
  const int col = (int)(i4 & 255);
  float s0 = 0.f, s1 = 0.f, s2 = 0.f, s3 = 0.f;
#pragma unroll
  for (int t = 0; t < 5; ++t) {
    ushort4 u = *(const ushort4*)(pA + (size_t)t * PSZ + i4);
    s0 += b2f(u.x); s1 += b2f(u.y); s2 += b2f(u.z); s3 += b2f(u.w);
  }
#pragma unroll
  for (int t = 0; t < 4; ++t) {
    ushort4 u = *(const ushort4*)(pB + (size_t)t * PSZ + i4);
    s0 += b2f(u.x); s1 += b2f(u.y); s2 += b2f(u.z); s3 += b2f(u.w);
  }
  const float4 b4 = *(const float4*)(bias + col);
  ushort4 st = make_ushort4(f2b(gelu_tanh(s0 + b4.x)), f2b(gelu_tanh(s1 + b4.y)),
                            f2b(gelu_tanh(s2 + b4.z)), f2b(gelu_tanh(s3 + b4.w)));
  *(ushort4*)(f1 + i4) = st;
}

// ---------------- fused flash attention: swapped QK^T, KVBLK=64, defer-max ---------
__global__ __launch_bounds__(256) void attn_kernel(
    const u16* __restrict__ q, const u16* __restrict__ k,
    const u16* __restrict__ vt, u16* __restrict__ o) {
  __shared__ u16 Plds[4][1024];
  const int tid = threadIdx.x;
  const int w = tid >> 6, l = tid & 63;
  const int lr = l & 15, lg = l >> 4;
  const int lg4 = lg * 4;
  const int bh = blockIdx.y;
  const int b = bh >> 4, h = bh & 15;
  const int qt = blockIdx.x;

  const u16* qp = q + (size_t)bh * NN * DD;
  const u16* kp = k + (size_t)bh * NN * DD;
  const u16* vp = vt + (size_t)bh * DD * VROW;

  const int qrow = qt * 64 + w * 16 + lr;
  const int qrc = qrow < NN ? qrow : NN - 1;
  const bf16x8 qf0 = ldfrag(qp + (size_t)qrc * DD + lg * 8);
  const bf16x8 qf1 = ldfrag(qp + (size_t)qrc * DD + 32 + lg * 8);

  f32x4 oa[4] = {};
  float mrow = -1e30f;
  float lsum = 0.f;

  u16* pw = Plds[w];

  for (int kt = 0; kt < 10; ++kt) {
    const int kb = kt * 64;
    bf16x8 kf0[4], kf1[4];
#pragma unroll
    for (int g = 0; g < 4; ++g) {
      int row = kb + g * 16 + lr;
      row = row < NN ? row : NN - 1;
      const u16* krp = kp + (size_t)row * DD;
      kf0[g] = ldfrag(krp + lg * 8);
      kf1[g] = ldfrag(krp + 32 + lg * 8);
    }
    f32x4 s[4] = {};
#pragma unroll
    for (int g = 0; g < 4; ++g) {
      s[g] = mfma16(kf0[g], qf0, s[g]);
      s[g] = mfma16(kf1[g], qf1, s[g]);
    }
    float t[16];
    if (kt == 9) {
#pragma unroll
      for (int g = 0; g < 4; ++g)
#pragma unroll
        for (int r = 0; r < 4; ++r)
          t[g * 4 + r] = (kb + g * 16 + lg4 + r < NN) ? s[g][r] : -3e38f;
    } else {
#pragma unroll
      for (int g = 0; g < 4; ++g)
#pragma unroll
        for (int r = 0; r < 4; ++r) t[g * 4 + r] = s[g][r];
    }
    float pmax = t[0];
#pragma unroll
    for (int i = 1; i < 16; ++i) pmax = fmaxf(pmax, t[i]);
    pmax = fmaxf(pmax, __shfl_xor(pmax, 16));
    pmax = fmaxf(pmax, __shfl_xor(pmax, 32));
    if (!__all(pmax <= mrow + 8.f)) {
      const float mn = fmaxf(mrow, pmax);
      const float corr = exp2f(mrow - mn);
      mrow = mn;
      lsum *= corr;
      float bc[4];
#pragma unroll
      for (int r = 0; r < 4; ++r) bc[r] = __shfl(corr, (l & 48) | (lg4 + r));
#pragma unroll
      for (int g = 0; g < 4; ++g)
#pragma unroll
        for (int r = 0; r < 4; ++r) oa[g][r] *= bc[r];
    }
    float ps[16];
    float rsum = 0.f;
#pragma unroll
    for (int i = 0; i < 16; ++i) { ps[i] = exp2f(t[i] - mrow); rsum += ps[i]; }
    rsum += __shfl_xor(rsum, 16);
    rsum += __shfl_xor(rsum, 32);
    lsum += rsum;
#pragma unroll
    for (int g = 0; g < 4; ++g) {
      u32 w0, w1;
      asm("v_cvt_pk_bf16_f32 %0, %1, %2" : "=v"(w0) : "v"(ps[g * 4 + 0]), "v"(ps[g * 4 + 1]));
      asm("v_cvt_pk_bf16_f32 %0, %1, %2" : "=v"(w1) : "v"(ps[g * 4 + 2]), "v"(ps[g * 4 + 3]));
      const int off = (g >> 1) * 512 + lr * 32 + (g & 1) * 16 + lg4;
      *(uint2*)(&pw[off]) = make_uint2(w0, w1);
    }
    asm volatile("s_waitcnt lgkmcnt(0)" ::: "memory");
    const bf16x8 paf = ldfrag(&pw[lr * 32 + lg * 8]);
    const bf16x8 pbf = ldfrag(&pw[512 + lr * 32 + lg * 8]);
#pragma unroll
    for (int dg = 0; dg < 4; ++dg) {
      const u16* vr = vp + (size_t)(dg * 16 + lr) * VROW + kb;
      oa[dg] = mfma16(paf, ldfrag(vr + lg * 8), oa[dg]);
      oa[dg] = mfma16(pbf, ldfrag(vr + 32 + lg * 8), oa[dg]);
    }
  }
  const int nq = qt * 64 + w * 16 + lg4;
  float linv[4];
#pragma unroll
  for (int r = 0; r < 4; ++r) linv[r] = __shfl(lsum, (l & 48) | (lg4 + r));
#pragma unroll
  for (int r = 0; r < 4; ++r) {
    const int n = nq + r;
    if (n >= NN) continue;
    const float inv = 1.0f / linv[r];
#pragma unroll
    for (int g = 0; g < 4; ++g)
      o[(size_t)(b * NN + n) * CC + h * DD + g * 16 + lr] = f2b(oa[g][r] * inv);
  }
}

// =====================================================================================
extern "C" void kernel_launch(void* const* d_in, const int* in_sizes, int n_in,
                              void* d_out, int out_size, void* d_ws, size_t ws_size,
                              hipStream_t stream) {
  const float* x     = (const float*)d_in[0];
  const float* ln1_g = (const float*)d_in[1];
  const float* ln1_b = (const float*)d_in[2];
  const float* in_w  = (const float*)d_in[3];
  const float* in_b  = (const float*)d_in[4];
  const float* out_w = (const float*)d_in[5];
  const float* out_b = (const float*)d_in[6];
  const float* ln2_g = (const float*)d_in[7];
  const float* ln2_b = (const float*)d_in[8];
  const float* c1w   = (const float*)d_in[9];
  const float* c1b   = (const float*)d_in[10];
  const float* c2w   = (const float*)d_in[11];
  const float* c2b   = (const float*)d_in[12];
  float* out = (float*)d_out;

  char* ws = (char*)d_ws;
  size_t off = 0;
  auto alloc = [&](size_t bytes) {
    void* p = ws + off;
    off += (bytes + 255) & ~(size_t)255;
    return p;
  };
  u16* hb   = (u16*)alloc((size_t)BN * CC * 2);
  u16* wqkv = (u16*)alloc((size_t)3072 * 1024 * 2);
  u16* wout = (u16*)alloc((size_t)1024 * 1024 * 2);
  u16* w1t  = (u16*)alloc((size_t)256 * 9216 * 2);
  u16* w2t  = (u16*)alloc((size_t)1024 * 2304 * 2);
  u16* qb   = (u16*)alloc((size_t)256 * NN * DD * 2);
  u16* kb   = (u16*)alloc((size_t)256 * NN * DD * 2);
  u16* vtb  = (u16*)alloc((size_t)256 * DD * VROW * 2 + 128);
  float* x2 = (float*)alloc((size_t)BN * CC * 4);
  u16* zpad = (u16*)alloc(256);
  u16* ob = hb;
  u16* yb = qb;
  u16* f1 = kb;
  u16* pA = hb;
  u16* pB = vtb;

  prep_kernel<<<1024, 256, 0, stream>>>(in_w, out_w, c1w, c2w, wqkv, wout, w1t, w2t, zpad);
  ln_kernel<0><<<BN, 256, 0, stream>>>(x, ln1_g, ln1_b, hb, nullptr);
  {
    GArgs a{hb, wqkv, in_b, nullptr, nullptr, nullptr, qb, kb, vtb, zpad, BN, CC};
    gemm_kernel<0><<<dim3(24, 73), 256, 0, stream>>>(a);
  }
  attn_kernel<<<dim3(10, 256), 256, 0, stream>>>(qb, kb, vtb, ob);
  {
    GArgs a{ob, wout, out_b, x, x2, nullptr, nullptr, nullptr, nullptr, zpad, BN, CC};
    gemm_kernel<1><<<dim3(8, 73), 256, 0, stream>>>(a);
  }
  ln_kernel<1><<<BN, 256, 0, stream>>>(x2, ln2_g, ln2_b, yb, out);
  {
    GArgs a{yb, w1t, c1b, nullptr, nullptr, pA, pB, nullptr, nullptr, zpad, 9216, 9216};
    gemm_kernel<4><<<dim3(2, 72, 9), 256, 0, stream>>>(a);
  }
  gelu_reduce_kernel<<<2304, 256, 0, stream>>>(pA, pB, c1b, f1);
  {
    GArgs a{f1, w2t, c2b, x2, out, nullptr, nullptr, nullptr, nullptr, zpad, 9216, 2304};
    gemm_kernel<3><<<dim3(8, 72), 256, 0, stream>>>(a);
  }
}

// Round 6
// 457.871 us; speedup vs baseline: 1.1795x; 1.1795x over previous
//
#include <hip/hip_runtime.h>

typedef unsigned short u16;
typedef unsigned int u32;
typedef __bf16 bf16x8 __attribute__((ext_vector_type(8)));
typedef float f32x4 __attribute__((ext_vector_type(4)));

#define DEVI __device__ __forceinline__

#define BB 16
#define NN 577
#define CC 1024
#define HH 16
#define DD 64
#define BN 9232     // B*N rows
#define PIX 576     // 24*24
#define WW 24
#define CHN 256
#define VROW 584    // padded v^T row length (16B-aligned rows)
#define PSZ (9216 * 256)  // one conv1 partial (elements)

DEVI u16 f2b(float f) {
  u32 u = __builtin_bit_cast(u32, f);
  u32 r = 0x7FFFu + ((u >> 16) & 1u);
  return (u16)((u + r) >> 16);
}

DEVI float b2f(u16 h) { return __builtin_bit_cast(float, (u32)h << 16); }

DEVI bf16x8 ldfrag(const u16* p) {
  uint4 u = *(const uint4*)p;
  return __builtin_bit_cast(bf16x8, u);
}

DEVI f32x4 mfma16(bf16x8 a, bf16x8 b, f32x4 c) {
  return __builtin_amdgcn_mfma_f32_16x16x32_bf16(a, b, c, 0, 0, 0);
}

DEVI void gld_lds16(const u16* g, u16* l) {
  __builtin_amdgcn_global_load_lds((const __attribute__((address_space(1))) void*)g,
                                   (__attribute__((address_space(3))) void*)l, 16, 0, 0);
}

DEVI float gelu_tanh(float v) {
  const float x3 = v * v * v;
  const float t = __expf(1.5957691216057308f * (v + 0.044715f * x3));
  const float th = (t - 1.f) / (t + 1.f);
  return 0.5f * v * (1.f + th);
}

// ---------------- prep: weight bf16 conversion + conv-weight permute + zero page ----
__global__ __launch_bounds__(256) void prep_kernel(
    const float* __restrict__ in_w, const float* __restrict__ out_w,
    const float* __restrict__ c1w, const float* __restrict__ c2w,
    u16* __restrict__ wqkv, u16* __restrict__ wout,
    u16* __restrict__ w1t, u16* __restrict__ w2t, u16* __restrict__ zpad) {
  const int i0 = blockIdx.x * 256 + threadIdx.x;
  const int stride = gridDim.x * 256;
  for (int i = i0; i < 3072 * 1024; i += stride) wqkv[i] = f2b(in_w[i]);
  for (int i = i0; i < 1024 * 1024; i += stride) wout[i] = f2b(out_w[i]);
  for (int i = i0; i < 256 * 9216; i += stride) {
    int oc = i / 9216, rem = i - oc * 9216, tap = rem >> 10, c = rem & 1023;
    w1t[i] = f2b(c1w[(size_t)oc * 9216 + c * 9 + tap]);
  }
  for (int i = i0; i < 1024 * 2304; i += stride) {
    int oc = i / 2304, rem = i - oc * 2304, tap = rem >> 8, c = rem & 255;
    w2t[i] = f2b(c2w[(size_t)oc * 2304 + c * 9 + tap]);
  }
  if (i0 < 128) zpad[i0] = 0;
}

// ---------------- LayerNorm (row of 1024), writes bf16; MODE1 also writes cls rows to out
template <int MODE>
__global__ __launch_bounds__(256) void ln_kernel(
    const float* __restrict__ xin, const float* __restrict__ gam,
    const float* __restrict__ bet, u16* __restrict__ yout, float* __restrict__ oextra) {
  __shared__ float sh[8];
  const int row = blockIdx.x;
  const int tid = threadIdx.x;
  const float4 v = ((const float4*)(xin + (size_t)row * CC))[tid];
  float s = v.x + v.y + v.z + v.w;
  float qq = v.x * v.x + v.y * v.y + v.z * v.z + v.w * v.w;
#pragma unroll
  for (int off = 32; off > 0; off >>= 1) {
    s += __shfl_down(s, off);
    qq += __shfl_down(qq, off);
  }
  if ((tid & 63) == 0) { sh[tid >> 6] = s; sh[4 + (tid >> 6)] = qq; }
  __syncthreads();
  s = sh[0] + sh[1] + sh[2] + sh[3];
  qq = sh[4] + sh[5] + sh[6] + sh[7];
  const float mu = s * (1.f / 1024.f);
  const float rstd = rsqrtf(qq * (1.f / 1024.f) - mu * mu + 1e-5f);
  const float4 g4 = ((const float4*)gam)[tid];
  const float4 b4 = ((const float4*)bet)[tid];
  const float o0 = (v.x - mu) * rstd * g4.x + b4.x;
  const float o1 = (v.y - mu) * rstd * g4.y + b4.y;
  const float o2 = (v.z - mu) * rstd * g4.z + b4.z;
  const float o3 = (v.w - mu) * rstd * g4.w + b4.w;
  ushort4 st = make_ushort4(f2b(o0), f2b(o1), f2b(o2), f2b(o3));
  *(ushort4*)(yout + (size_t)row * CC + tid * 4) = st;
  if constexpr (MODE == 1) {
    if (row % NN == NN - 1) {
      float4 ov = make_float4(v.x + o0, v.y + o1, v.z + o2, v.w + o3);
      ((float4*)(oextra + (size_t)row * CC))[tid] = ov;
    }
  }
}

// ---------------- 128x128 MFMA GEMM, BK=32, 3-buffer depth-2 pipeline (48 KB LDS) ---
// MODE 0: QKV   -> q(pre-scaled),k (b,h,n,d) + v^T (b,h,d,n) via LDS transpose
// MODE 1: PROJ  -> x2 = acc + bias + res  (f32)
// MODE 3: CONV2 -> out = acc + bias + x2 (f32, row remap)
// MODE 4: CONV1 split-K by tap -> bf16 partial
struct GArgs {
  const u16* A; const u16* Bm; const float* bias; const float* res;
  float* outF; u16* outH; u16* outQ; u16* outK; u16* outV; const u16* zpad;
  int M, K;
};

template <int MODE>
__global__ __launch_bounds__(256) void gemm_kernel(GArgs ag) {
  __shared__ u16 SH[24576];  // 48 KB: A bufs [0,12288), B bufs [12288,24576)
  const int tid = threadIdx.x;
  const int w = tid >> 6, l = tid & 63;
  const int wr = w >> 1, wc = w & 1;
  const int lr = l & 15, lg = l >> 4;
  const int m0 = blockIdx.x * 128, n0 = blockIdx.y * 128;
  const int tapz = (MODE == 4) ? blockIdx.z : 0;
  const int rA = w * 16 + (l >> 2);
  const int cbs = ((l & 3) ^ ((l >> 3) & 3)) * 8;  // source-side XOR (LDS stays linear)

  auto stage = [&](int buf, int kt) {
    const int k0 = kt * 32;
    u16* Ald = SH + buf * 4096;
    u16* Bld = SH + 12288 + buf * 4096;
#pragma unroll
    for (int c = 0; c < 2; ++c) {
      const int r = c * 64 + rA;
      const u16* asrc;
      if constexpr (MODE <= 1) {
        int m = m0 + r;
        m = m < ag.M ? m : ag.M - 1;
        asrc = ag.A + (size_t)m * ag.K + (k0 + cbs);
      } else {
        const int m = m0 + r;
        const int b = m / PIX, p = m - b * PIX;
        const int py = p / WW, px = p - py * WW;
        constexpr int CKc = (MODE == 3) ? 256 : 1024;
        const int tap = (MODE == 4) ? tapz : (k0 / CKc);
        const int c0 = (MODE == 4) ? k0 : (k0 - tap * CKc);
        const int py2 = py + (tap / 3) - 1, px2 = px + (tap % 3) - 1;
        if ((u32)py2 < (u32)WW && (u32)px2 < (u32)WW) {
          if constexpr (MODE == 4)
            asrc = ag.A + ((size_t)(b * NN + py2 * WW + px2) * CC + c0 + cbs);
          else
            asrc = ag.A + ((size_t)(b * PIX + py2 * WW + px2) * CHN + c0 + cbs);
        } else {
          asrc = ag.zpad + cbs;
        }
      }
      gld_lds16(asrc, &Ald[c * 2048 + w * 512]);
      const u16* bsrc;
      if constexpr (MODE == 4)
        bsrc = ag.Bm + (size_t)(n0 + r) * 9216 + (tapz * 1024 + k0 + cbs);
      else
        bsrc = ag.Bm + (size_t)(n0 + r) * ag.K + (k0 + cbs);
      gld_lds16(bsrc, &Bld[c * 2048 + w * 512]);
    }
  };

  f32x4 acc[4][4] = {};
  const int KL = (MODE == 4) ? 1024 : ag.K;
  const int nst = KL >> 5;  // >= 32 for all modes

  stage(0, 0);
  stage(1, 1);

  const int swz = (lr >> 1) & 3;
  int b0 = 0, b1 = 1, b2 = 2;
  for (int kt = 0; kt < nst; ++kt) {
    // tile kt resident after this wait; tile kt+1 (4 loads) stays in flight
    if (kt + 1 < nst) { asm volatile("s_waitcnt vmcnt(4)" ::: "memory"); }
    else              { asm volatile("s_waitcnt vmcnt(0)" ::: "memory"); }
    __builtin_amdgcn_s_barrier();
    if (kt + 2 < nst) stage(b2, kt + 2);
    bf16x8 af[4], bfr[4];
#pragma unroll
    for (int i = 0; i < 4; ++i)
      af[i] = ldfrag(&SH[b0 * 4096 + (wr * 64 + i * 16 + lr) * 32 + ((lg ^ swz) * 8)]);
#pragma unroll
    for (int i = 0; i < 4; ++i)
      bfr[i] = ldfrag(&SH[12288 + b0 * 4096 + (wc * 64 + i * 16 + lr) * 32 + ((lg ^ swz) * 8)]);
    __builtin_amdgcn_s_setprio(1);
#pragma unroll
    for (int mi = 0; mi < 4; ++mi)
#pragma unroll
      for (int ni = 0; ni < 4; ++ni) acc[mi][ni] = mfma16(af[mi], bfr[ni], acc[mi][ni]);
    __builtin_amdgcn_s_setprio(0);
    const int tmp = b0; b0 = b1; b1 = b2; b2 = tmp;
  }

  // ---------------- epilogue ----------------
  if constexpr (MODE == 0) {
    if (n0 >= 2048) {
      // v block: transpose 64x64 wave-quadrants in LDS, write v^T n-contiguous
      __syncthreads();  // all K-loop LDS traffic drained; SH reusable
      const int G0 = m0 + wr * 64;
      const int b0q = G0 / NN;
      const bool ok = (G0 + 63 < ag.M) && (b0q == (G0 + 63) / NN);
      const int h = (n0 + wc * 64 - 2048) >> 6;
      u16* scr = SH + w * 5120;  // 64 x 80 u16 per wave
      if (ok) {
#pragma unroll
        for (int mi = 0; mi < 4; ++mi) {
#pragma unroll
          for (int ni = 0; ni < 4; ++ni) {
            ushort4 st;
            const float bv = ag.bias[n0 + wc * 64 + ni * 16 + lr];
            st.x = f2b(acc[mi][ni][0] + bv);
            st.y = f2b(acc[mi][ni][1] + bv);
            st.z = f2b(acc[mi][ni][2] + bv);
            st.w = f2b(acc[mi][ni][3] + bv);
            *(ushort4*)(scr + (ni * 16 + lr) * 80 + mi * 16 + lg * 4) = st;
          }
        }
        asm volatile("s_waitcnt lgkmcnt(0)" ::: "memory");  // wave-local transpose
        const int nb = G0 - b0q * NN;
        u16* vb = ag.outV + (size_t)((b0q * 16 + h) * 64) * VROW;
#pragma unroll
        for (int pass = 0; pass < 8; ++pass) {
          const int d_ = pass * 8 + (l >> 3);
          const int nn = (l & 7) * 8;
          uint4 vv = *(const uint4*)(scr + d_ * 80 + nn);
          u16* dst = vb + (size_t)d_ * VROW + nb + nn;
          if (!(nb & 1)) {
            ((u32*)dst)[0] = vv.x; ((u32*)dst)[1] = vv.y;
            ((u32*)dst)[2] = vv.z; ((u32*)dst)[3] = vv.w;
          } else {
            u16 tmp[8];
            *(uint4*)tmp = vv;
#pragma unroll
            for (int j = 0; j < 8; ++j) dst[j] = tmp[j];
          }
        }
      } else {
#pragma unroll
        for (int mi = 0; mi < 4; ++mi) {
#pragma unroll
          for (int r = 0; r < 4; ++r) {
            const int row = G0 + mi * 16 + lg * 4 + r;
            if (row >= ag.M) continue;
            const int b = row / NN, n = row - b * NN;
#pragma unroll
            for (int ni = 0; ni < 4; ++ni) {
              const int col = n0 + wc * 64 + ni * 16 + lr;
              const int d = col & 63;
              const float v = acc[mi][ni][r] + ag.bias[col];
              ag.outV[((size_t)((b * 16 + h) * 64 + d)) * VROW + n] = f2b(v);
            }
          }
        }
      }
      return;
    }
#pragma unroll
    for (int mi = 0; mi < 4; ++mi) {
#pragma unroll
      for (int r = 0; r < 4; ++r) {
        const int row = m0 + wr * 64 + mi * 16 + lg * 4 + r;
        if (row >= ag.M) continue;
        const int b = row / NN, n = row - b * NN;
#pragma unroll
        for (int ni = 0; ni < 4; ++ni) {
          const int col = n0 + wc * 64 + ni * 16 + lr;
          const int which = col >> 10, hd = col & 1023, h = hd >> 6, d = hd & 63;
          const float v = acc[mi][ni][r] + ag.bias[col];
          if (which == 0)
            ag.outQ[((size_t)(b * 16 + h) * NN + n) * DD + d] = f2b(v * 0.18033688011112042f);
          else
            ag.outK[((size_t)(b * 16 + h) * NN + n) * DD + d] = f2b(v);
        }
      }
    }
  } else {
#pragma unroll
    for (int mi = 0; mi < 4; ++mi) {
#pragma unroll
      for (int r = 0; r < 4; ++r) {
        const int row = m0 + wr * 64 + mi * 16 + lg * 4 + r;
        if (row >= ag.M) continue;
#pragma unroll
        for (int ni = 0; ni < 4; ++ni) {
          const int col = n0 + wc * 64 + ni * 16 + lr;
          if constexpr (MODE == 4) {
            u16* pb = (tapz < 5) ? ag.outH : ag.outQ;
            const int tl = (tapz < 5) ? tapz : tapz - 5;
            pb[(size_t)tl * PSZ + (size_t)row * CHN + col] = f2b(acc[mi][ni][r]);
          } else {
            const float v = acc[mi][ni][r] + ag.bias[col];
            if constexpr (MODE == 1) {
              const size_t idx = (size_t)row * CC + col;
              ag.outF[idx] = v + ag.res[idx];
            } else {
              const int b = row / PIX, p = row - b * PIX;
              const size_t idx = (size_t)(b * NN + p) * CC + col;
              ag.outF[idx] = v + ag.res[idx];
            }
          }
        }
      }
    }
  }
}

// ---------------- conv1 reduce: f1 = gelu(sum of 9 bf16 partials + bias) -> bf16 ----
__global__ __launch_bounds__(256) void gelu_reduce_kernel(
    const u16* __restrict__ pA, const u16* __restrict__ pB,
    const float* __restrict__ bias, u16* __restrict__ f1) {
  const size_t i4 = ((size_t)blockIdx.x * 256 + threadIdx.x) * 4;
  const int col = (int)(i4 & 255);
  float s0 = 0.f, s1 = 0.f, s2 = 0.f, s3 = 0.f;
#pragma unroll
  for (int t = 0; t < 5; ++t) {
    ushort4 u = *(const ushort4*)(pA + (size_t)t * PSZ + i4);
    s0 += b2f(u.x); s1 += b2f(u.y); s2 += b2f(u.z); s3 += b2f(u.w);
  }
#pragma unroll
  for (int t = 0; t < 4; ++t) {
    ushort4 u = *(const ushort4*)(pB + (size_t)t * PSZ + i4);
    s0 += b2f(u.x); s1 += b2f(u.y); s2 += b2f(u.z); s3 += b2f(u.w);
  }
  const float4 b4 = *(const float4*)(bias + col);
  ushort4 st = make_ushort4(f2b(gelu_tanh(s0 + b4.x)), f2b(gelu_tanh(s1 + b4.y)),
                            f2b(gelu_tanh(s2 + b4.z)), f2b(gelu_tanh(s3 + b4.w)));
  *(ushort4*)(f1 + i4) = st;
}

// ---------------- fused flash attention: swapped QK^T, KVBLK=64, defer-max ---------
// XCD-swizzled 1-D grid: all 10 q-tiles of one (b,h) land on one XCD (K/V L2-hot).
// P-LDS path pair-XOR swizzled (granule ^= ((row>>1)&3)<<1): 2-way banks, free.
// V loads hoisted before softmax; next-tile K prefetched via unroll-by-2 reg sets.
__global__ __launch_bounds__(256) void attn_kernel(
    const u16* __restrict__ q, const u16* __restrict__ k,
    const u16* __restrict__ vt, u16* __restrict__ o) {
  __shared__ u16 Plds[4][1024];
  const int tid = threadIdx.x;
  const int w = tid >> 6, l = tid & 63;
  const int lr = l & 15, lg = l >> 4;
  const int lg4 = lg * 4;
  const int bid = blockIdx.x;
  const int xcd = bid & 7, gg = bid >> 3;
  const int bh = (gg / 10) * 8 + xcd;   // 0..255, bh%8 == xcd
  const int qt = gg % 10;
  const int b = bh >> 4, h = bh & 15;

  const u16* qp = q + (size_t)bh * NN * DD;
  const u16* kp = k + (size_t)bh * NN * DD;
  const u16* vp = vt + (size_t)bh * DD * VROW;

  const int qrow = qt * 64 + w * 16 + lr;
  const int qrc = qrow < NN ? qrow : NN - 1;
  const bf16x8 qf0 = ldfrag(qp + (size_t)qrc * DD + lg * 8);
  const bf16x8 qf1 = ldfrag(qp + (size_t)qrc * DD + 32 + lg * 8);

  f32x4 oa[4] = {};
  float mrow = -1e30f;
  float lsum = 0.f;
  u16* pw = Plds[w];
  const int swz2 = (lr >> 1) & 3;

  auto loadK = [&](int kt, bf16x8 (&k0)[4], bf16x8 (&k1)[4]) {
    const int kb = kt * 64;
#pragma unroll
    for (int g = 0; g < 4; ++g) {
      int row = kb + g * 16 + lr;
      row = row < NN ? row : NN - 1;
      const u16* krp = kp + (size_t)row * DD;
      k0[g] = ldfrag(krp + lg * 8);
      k1[g] = ldfrag(krp + 32 + lg * 8);
    }
  };

  auto iter = [&](int kt, bf16x8 (&ck0)[4], bf16x8 (&ck1)[4],
                  bf16x8 (&nk0)[4], bf16x8 (&nk1)[4]) {
    const int kb = kt * 64;
    f32x4 s[4] = {};
#pragma unroll
    for (int g = 0; g < 4; ++g) {
      s[g] = mfma16(ck0[g], qf0, s[g]);   // swapped: scores^T, col = q-row = lr
      s[g] = mfma16(ck1[g], qf1, s[g]);
    }
    if (kt < 9) loadK(kt + 1, nk0, nk1);  // prefetch next K tile
    bf16x8 vf0[4], vf1[4];                // hoist V loads: latency hides under softmax
#pragma unroll
    for (int dg = 0; dg < 4; ++dg) {
      const u16* vr = vp + (size_t)(dg * 16 + lr) * VROW + kb;
      vf0[dg] = ldfrag(vr + lg * 8);
      vf1[dg] = ldfrag(vr + 32 + lg * 8);
    }
    float t[16];
    const bool last = (kt == 9);
#pragma unroll
    for (int g = 0; g < 4; ++g)
#pragma unroll
      for (int r = 0; r < 4; ++r) {
        const int key = kb + g * 16 + lg4 + r;
        t[g * 4 + r] = (!last || key < NN) ? s[g][r] : -3e38f;
      }
    float pmax = t[0];
#pragma unroll
    for (int i = 1; i < 16; ++i) pmax = fmaxf(pmax, t[i]);
    pmax = fmaxf(pmax, __shfl_xor(pmax, 16));
    pmax = fmaxf(pmax, __shfl_xor(pmax, 32));
    if (!__all(pmax <= mrow + 8.f)) {   // defer-max
      const float mn = fmaxf(mrow, pmax);
      const float corr = exp2f(mrow - mn);
      mrow = mn;
      lsum *= corr;
      float bc[4];
#pragma unroll
      for (int r = 0; r < 4; ++r) bc[r] = __shfl(corr, (l & 48) | (lg4 + r));
#pragma unroll
      for (int g = 0; g < 4; ++g)
#pragma unroll
        for (int r = 0; r < 4; ++r) oa[g][r] *= bc[r];
    }
    float ps[16];
    float rsum = 0.f;
#pragma unroll
    for (int i = 0; i < 16; ++i) { ps[i] = exp2f(t[i] - mrow); rsum += ps[i]; }
    rsum += __shfl_xor(rsum, 16);
    rsum += __shfl_xor(rsum, 32);
    lsum += rsum;
    // P -> LDS, pair-XOR swizzled: physical granule = logical ^ ((row>>1)&3)<<1
#pragma unroll
    for (int g = 0; g < 4; ++g) {
      u32 w0, w1;
      asm("v_cvt_pk_bf16_f32 %0, %1, %2" : "=v"(w0) : "v"(ps[g * 4 + 0]), "v"(ps[g * 4 + 1]));
      asm("v_cvt_pk_bf16_f32 %0, %1, %2" : "=v"(w1) : "v"(ps[g * 4 + 2]), "v"(ps[g * 4 + 3]));
      const int gi = ((g & 1) * 4 + lg) ^ (swz2 << 1);
      const int off = (g >> 1) * 512 + lr * 32 + gi * 4;
      *(uint2*)(&pw[off]) = make_uint2(w0, w1);
    }
    asm volatile("s_waitcnt lgkmcnt(0)" ::: "memory");
    const int pp = (lg ^ swz2) * 8;
    const bf16x8 paf = ldfrag(&pw[lr * 32 + pp]);
    const bf16x8 pbf = ldfrag(&pw[512 + lr * 32 + pp]);
#pragma unroll
    for (int dg = 0; dg < 4; ++dg) {
      oa[dg] = mfma16(paf, vf0[dg], oa[dg]);
      oa[dg] = mfma16(pbf, vf1[dg], oa[dg]);
    }
  };

  bf16x8 ka0[4], ka1[4], kb0[4], kb1[4];
  loadK(0, ka0, ka1);
  for (int kt2 = 0; kt2 < 5; ++kt2) {
    iter(kt2 * 2,     ka0, ka1, kb0, kb1);
    iter(kt2 * 2 + 1, kb0, kb1, ka0, ka1);
  }

  const int nq = qt * 64 + w * 16 + lg4;
  float linv[4];
#pragma unroll
  for (int r = 0; r < 4; ++r) linv[r] = __shfl(lsum, (l & 48) | (lg4 + r));
#pragma unroll
  for (int r = 0; r < 4; ++r) {
    const int n = nq + r;
    if (n >= NN) continue;
    const float inv = 1.0f / linv[r];
#pragma unroll
    for (int g = 0; g < 4; ++g)
      o[(size_t)(b * NN + n) * CC + h * DD + g * 16 + lr] = f2b(oa[g][r] * inv);
  }
}

// =====================================================================================
extern "C" void kernel_launch(void* const* d_in, const int* in_sizes, int n_in,
                              void* d_out, int out_size, void* d_ws, size_t ws_size,
                              hipStream_t stream) {
  const float* x     = (const float*)d_in[0];
  const float* ln1_g = (const float*)d_in[1];
  const float* ln1_b = (const float*)d_in[2];
  const float* in_w  = (const float*)d_in[3];
  const float* in_b  = (const float*)d_in[4];
  const float* out_w = (const float*)d_in[5];
  const float* out_b = (const float*)d_in[6];
  const float* ln2_g = (const float*)d_in[7];
  const float* ln2_b = (const float*)d_in[8];
  const float* c1w   = (const float*)d_in[9];
  const float* c1b   = (const float*)d_in[10];
  const float* c2w   = (const float*)d_in[11];
  const float* c2b   = (const float*)d_in[12];
  float* out = (float*)d_out;

  char* ws = (char*)d_ws;
  size_t off = 0;
  auto alloc = [&](size_t bytes) {
    void* p = ws + off;
    off += (bytes + 255) & ~(size_t)255;
    return p;
  };
  u16* hb   = (u16*)alloc((size_t)BN * CC * 2);
  u16* wqkv = (u16*)alloc((size_t)3072 * 1024 * 2);
  u16* wout = (u16*)alloc((size_t)1024 * 1024 * 2);
  u16* w1t  = (u16*)alloc((size_t)256 * 9216 * 2);
  u16* w2t  = (u16*)alloc((size_t)1024 * 2304 * 2);
  u16* qb   = (u16*)alloc((size_t)256 * NN * DD * 2);
  u16* kb   = (u16*)alloc((size_t)256 * NN * DD * 2);
  u16* vtb  = (u16*)alloc((size_t)256 * DD * VROW * 2 + 256);
  float* x2 = (float*)alloc((size_t)BN * CC * 4);
  u16* zpad = (u16*)alloc(256);
  u16* ob = hb;
  u16* yb = qb;
  u16* f1 = kb;
  u16* pA = hb;
  u16* pB = vtb;

  prep_kernel<<<1024, 256, 0, stream>>>(in_w, out_w, c1w, c2w, wqkv, wout, w1t, w2t, zpad);
  ln_kernel<0><<<BN, 256, 0, stream>>>(x, ln1_g, ln1_b, hb, nullptr);
  {
    GArgs a{hb, wqkv, in_b, nullptr, nullptr, nullptr, qb, kb, vtb, zpad, BN, CC};
    gemm_kernel<0><<<dim3(73, 24), 256, 0, stream>>>(a);
  }
  attn_kernel<<<2560, 256, 0, stream>>>(qb, kb, vtb, ob);
  {
    GArgs a{ob, wout, out_b, x, x2, nullptr, nullptr, nullptr, nullptr, zpad, BN, CC};
    gemm_kernel<1><<<dim3(73, 8), 256, 0, stream>>>(a);
  }
  ln_kernel<1><<<BN, 256, 0, stream>>>(x2, ln2_g, ln2_b, yb, out);
  {
    GArgs a{yb, w1t, c1b, nullptr, nullptr, pA, pB, nullptr, nullptr, zpad, 9216, 9216};
    gemm_kernel<4><<<dim3(72, 2, 9), 256, 0, stream>>>(a);
  }
  gelu_reduce_kernel<<<2304, 256, 0, stream>>>(pA, pB, c1b, f1);
  {
    GArgs a{f1, w2t, c2b, x2, out, nullptr, nullptr, nullptr, nullptr, zpad, 9216, 2304};
    gemm_kernel<3><<<dim3(72, 8), 256, 0, stream>>>(a);
  }
}

// Round 7
// 399.416 us; speedup vs baseline: 1.3521x; 1.1464x over previous
//
#include <hip/hip_runtime.h>

typedef unsigned short u16;
typedef unsigned int u32;
typedef __bf16 bf16x8 __attribute__((ext_vector_type(8)));
typedef float f32x4 __attribute__((ext_vector_type(4)));

#define DEVI __device__ __forceinline__

#define BB 16
#define NN 577
#define CC 1024
#define HH 16
#define DD 64
#define BN 9232     // B*N rows
#define PIX 576     // 24*24
#define WW 24
#define CHN 256
#define VROW 584    // padded v^T row length (16B-aligned rows)
#define PSZ (9216 * 256)  // one conv1 partial (elements)

DEVI u16 f2b(float f) {
  u32 u = __builtin_bit_cast(u32, f);
  u32 r = 0x7FFFu + ((u >> 16) & 1u);
  return (u16)((u + r) >> 16);
}

DEVI float b2f(u16 h) { return __builtin_bit_cast(float, (u32)h << 16); }

DEVI bf16x8 ldfrag(const u16* p) {
  uint4 u = *(const uint4*)p;
  return __builtin_bit_cast(bf16x8, u);
}

DEVI f32x4 mfma16(bf16x8 a, bf16x8 b, f32x4 c) {
  return __builtin_amdgcn_mfma_f32_16x16x32_bf16(a, b, c, 0, 0, 0);
}

DEVI void gld_lds16(const u16* g, u16* l) {
  __builtin_amdgcn_global_load_lds((const __attribute__((address_space(1))) void*)g,
                                   (__attribute__((address_space(3))) void*)l, 16, 0, 0);
}

DEVI float gelu_tanh(float v) {
  const float x3 = v * v * v;
  const float t = __expf(1.5957691216057308f * (v + 0.044715f * x3));
  const float th = (t - 1.f) / (t + 1.f);
  return 0.5f * v * (1.f + th);
}

// ---------------- prep: weight bf16 conversion + conv-weight permute + zero page ----
__global__ __launch_bounds__(256) void prep_kernel(
    const float* __restrict__ in_w, const float* __restrict__ out_w,
    const float* __restrict__ c1w, const float* __restrict__ c2w,
    u16* __restrict__ wqkv, u16* __restrict__ wout,
    u16* __restrict__ w1t, u16* __restrict__ w2t, u16* __restrict__ zpad) {
  const int i0 = blockIdx.x * 256 + threadIdx.x;
  const int stride = gridDim.x * 256;
  for (int i = i0; i < 3072 * 1024; i += stride) wqkv[i] = f2b(in_w[i]);
  for (int i = i0; i < 1024 * 1024; i += stride) wout[i] = f2b(out_w[i]);
  for (int i = i0; i < 256 * 9216; i += stride) {
    int oc = i / 9216, rem = i - oc * 9216, tap = rem >> 10, c = rem & 1023;
    w1t[i] = f2b(c1w[(size_t)oc * 9216 + c * 9 + tap]);
  }
  for (int i = i0; i < 1024 * 2304; i += stride) {
    int oc = i / 2304, rem = i - oc * 2304, tap = rem >> 8, c = rem & 255;
    w2t[i] = f2b(c2w[(size_t)oc * 2304 + c * 9 + tap]);
  }
  if (i0 < 128) zpad[i0] = 0;
}

// ---------------- LayerNorm (row of 1024), writes bf16; MODE1 also writes cls rows to out
template <int MODE>
__global__ __launch_bounds__(256) void ln_kernel(
    const float* __restrict__ xin, const float* __restrict__ gam,
    const float* __restrict__ bet, u16* __restrict__ yout, float* __restrict__ oextra) {
  __shared__ float sh[8];
  const int row = blockIdx.x;
  const int tid = threadIdx.x;
  const float4 v = ((const float4*)(xin + (size_t)row * CC))[tid];
  float s = v.x + v.y + v.z + v.w;
  float qq = v.x * v.x + v.y * v.y + v.z * v.z + v.w * v.w;
#pragma unroll
  for (int off = 32; off > 0; off >>= 1) {
    s += __shfl_down(s, off);
    qq += __shfl_down(qq, off);
  }
  if ((tid & 63) == 0) { sh[tid >> 6] = s; sh[4 + (tid >> 6)] = qq; }
  __syncthreads();
  s = sh[0] + sh[1] + sh[2] + sh[3];
  qq = sh[4] + sh[5] + sh[6] + sh[7];
  const float mu = s * (1.f / 1024.f);
  const float rstd = rsqrtf(qq * (1.f / 1024.f) - mu * mu + 1e-5f);
  const float4 g4 = ((const float4*)gam)[tid];
  const float4 b4 = ((const float4*)bet)[tid];
  const float o0 = (v.x - mu) * rstd * g4.x + b4.x;
  const float o1 = (v.y - mu) * rstd * g4.y + b4.y;
  const float o2 = (v.z - mu) * rstd * g4.z + b4.z;
  const float o3 = (v.w - mu) * rstd * g4.w + b4.w;
  ushort4 st = make_ushort4(f2b(o0), f2b(o1), f2b(o2), f2b(o3));
  *(ushort4*)(yout + (size_t)row * CC + tid * 4) = st;
  if constexpr (MODE == 1) {
    if (row % NN == NN - 1) {
      float4 ov = make_float4(v.x + o0, v.y + o1, v.z + o2, v.w + o3);
      ((float4*)(oextra + (size_t)row * CC))[tid] = ov;
    }
  }
}

// ---------------- 128x128 MFMA GEMM, BK=32, 3-buffer depth-2 pipeline (48 KB LDS) ---
struct GArgs {
  const u16* A; const u16* Bm; const float* bias; const float* res;
  float* outF; u16* outH; u16* outQ; u16* outK; u16* outV; const u16* zpad;
  int M, K;
};

template <int MODE>
__global__ __launch_bounds__(256) void gemm_kernel(GArgs ag) {
  __shared__ u16 SH[24576];  // 48 KB: A bufs [0,12288), B bufs [12288,24576)
  const int tid = threadIdx.x;
  const int w = tid >> 6, l = tid & 63;
  const int wr = w >> 1, wc = w & 1;
  const int lr = l & 15, lg = l >> 4;
  const int m0 = blockIdx.x * 128, n0 = blockIdx.y * 128;
  const int tapz = (MODE == 4) ? blockIdx.z : 0;
  const int rA = w * 16 + (l >> 2);
  const int cbs = ((l & 3) ^ ((l >> 3) & 3)) * 8;  // source-side XOR (LDS stays linear)

  auto stage = [&](int buf, int kt) {
    const int k0 = kt * 32;
    u16* Ald = SH + buf * 4096;
    u16* Bld = SH + 12288 + buf * 4096;
#pragma unroll
    for (int c = 0; c < 2; ++c) {
      const int r = c * 64 + rA;
      const u16* asrc;
      if constexpr (MODE <= 1) {
        int m = m0 + r;
        m = m < ag.M ? m : ag.M - 1;
        asrc = ag.A + (size_t)m * ag.K + (k0 + cbs);
      } else {
        const int m = m0 + r;
        const int b = m / PIX, p = m - b * PIX;
        const int py = p / WW, px = p - py * WW;
        constexpr int CKc = (MODE == 3) ? 256 : 1024;
        const int tap = (MODE == 4) ? tapz : (k0 / CKc);
        const int c0 = (MODE == 4) ? k0 : (k0 - tap * CKc);
        const int py2 = py + (tap / 3) - 1, px2 = px + (tap % 3) - 1;
        if ((u32)py2 < (u32)WW && (u32)px2 < (u32)WW) {
          if constexpr (MODE == 4)
            asrc = ag.A + ((size_t)(b * NN + py2 * WW + px2) * CC + c0 + cbs);
          else
            asrc = ag.A + ((size_t)(b * PIX + py2 * WW + px2) * CHN + c0 + cbs);
        } else {
          asrc = ag.zpad + cbs;
        }
      }
      gld_lds16(asrc, &Ald[c * 2048 + w * 512]);
      const u16* bsrc;
      if constexpr (MODE == 4)
        bsrc = ag.Bm + (size_t)(n0 + r) * 9216 + (tapz * 1024 + k0 + cbs);
      else
        bsrc = ag.Bm + (size_t)(n0 + r) * ag.K + (k0 + cbs);
      gld_lds16(bsrc, &Bld[c * 2048 + w * 512]);
    }
  };

  f32x4 acc[4][4] = {};
  const int KL = (MODE == 4) ? 1024 : ag.K;
  const int nst = KL >> 5;

  stage(0, 0);
  stage(1, 1);

  const int swz = (lr >> 1) & 3;
  int b0 = 0, b1 = 1, b2 = 2;
  for (int kt = 0; kt < nst; ++kt) {
    if (kt + 1 < nst) { asm volatile("s_waitcnt vmcnt(4)" ::: "memory"); }
    else              { asm volatile("s_waitcnt vmcnt(0)" ::: "memory"); }
    __builtin_amdgcn_s_barrier();
    if (kt + 2 < nst) stage(b2, kt + 2);
    bf16x8 af[4], bfr[4];
#pragma unroll
    for (int i = 0; i < 4; ++i)
      af[i] = ldfrag(&SH[b0 * 4096 + (wr * 64 + i * 16 + lr) * 32 + ((lg ^ swz) * 8)]);
#pragma unroll
    for (int i = 0; i < 4; ++i)
      bfr[i] = ldfrag(&SH[12288 + b0 * 4096 + (wc * 64 + i * 16 + lr) * 32 + ((lg ^ swz) * 8)]);
    __builtin_amdgcn_s_setprio(1);
#pragma unroll
    for (int mi = 0; mi < 4; ++mi)
#pragma unroll
      for (int ni = 0; ni < 4; ++ni) acc[mi][ni] = mfma16(af[mi], bfr[ni], acc[mi][ni]);
    __builtin_amdgcn_s_setprio(0);
    const int tmp = b0; b0 = b1; b1 = b2; b2 = tmp;
  }

  // ---------------- epilogue ----------------
  if constexpr (MODE == 0) {
    if (n0 >= 2048) {
      __syncthreads();
      const int G0 = m0 + wr * 64;
      const int b0q = G0 / NN;
      const bool ok = (G0 + 63 < ag.M) && (b0q == (G0 + 63) / NN);
      const int h = (n0 + wc * 64 - 2048) >> 6;
      u16* scr = SH + w * 5120;
      if (ok) {
#pragma unroll
        for (int mi = 0; mi < 4; ++mi) {
#pragma unroll
          for (int ni = 0; ni < 4; ++ni) {
            ushort4 st;
            const float bv = ag.bias[n0 + wc * 64 + ni * 16 + lr];
            st.x = f2b(acc[mi][ni][0] + bv);
            st.y = f2b(acc[mi][ni][1] + bv);
            st.z = f2b(acc[mi][ni][2] + bv);
            st.w = f2b(acc[mi][ni][3] + bv);
            *(ushort4*)(scr + (ni * 16 + lr) * 80 + mi * 16 + lg * 4) = st;
          }
        }
        asm volatile("s_waitcnt lgkmcnt(0)" ::: "memory");
        const int nb = G0 - b0q * NN;
        u16* vb = ag.outV + (size_t)((b0q * 16 + h) * 64) * VROW;
#pragma unroll
        for (int pass = 0; pass < 8; ++pass) {
          const int d_ = pass * 8 + (l >> 3);
          const int nn = (l & 7) * 8;
          uint4 vv = *(const uint4*)(scr + d_ * 80 + nn);
          u16* dst = vb + (size_t)d_ * VROW + nb + nn;
          if (!(nb & 1)) {
            ((u32*)dst)[0] = vv.x; ((u32*)dst)[1] = vv.y;
            ((u32*)dst)[2] = vv.z; ((u32*)dst)[3] = vv.w;
          } else {
            u16 tmp[8];
            *(uint4*)tmp = vv;
#pragma unroll
            for (int j = 0; j < 8; ++j) dst[j] = tmp[j];
          }
        }
      } else {
#pragma unroll
        for (int mi = 0; mi < 4; ++mi) {
#pragma unroll
          for (int r = 0; r < 4; ++r) {
            const int row = G0 + mi * 16 + lg * 4 + r;
            if (row >= ag.M) continue;
            const int b = row / NN, n = row - b * NN;
#pragma unroll
            for (int ni = 0; ni < 4; ++ni) {
              const int col = n0 + wc * 64 + ni * 16 + lr;
              const int d = col & 63;
              const float v = acc[mi][ni][r] + ag.bias[col];
              ag.outV[((size_t)((b * 16 + h) * 64 + d)) * VROW + n] = f2b(v);
            }
          }
        }
      }
      return;
    }
#pragma unroll
    for (int mi = 0; mi < 4; ++mi) {
#pragma unroll
      for (int r = 0; r < 4; ++r) {
        const int row = m0 + wr * 64 + mi * 16 + lg * 4 + r;
        if (row >= ag.M) continue;
        const int b = row / NN, n = row - b * NN;
#pragma unroll
        for (int ni = 0; ni < 4; ++ni) {
          const int col = n0 + wc * 64 + ni * 16 + lr;
          const int which = col >> 10, hd = col & 1023, h = hd >> 6, d = hd & 63;
          const float v = acc[mi][ni][r] + ag.bias[col];
          if (which == 0)
            ag.outQ[((size_t)(b * 16 + h) * NN + n) * DD + d] = f2b(v * 0.18033688011112042f);
          else
            ag.outK[((size_t)(b * 16 + h) * NN + n) * DD + d] = f2b(v);
        }
      }
    }
  } else {
#pragma unroll
    for (int mi = 0; mi < 4; ++mi) {
#pragma unroll
      for (int r = 0; r < 4; ++r) {
        const int row = m0 + wr * 64 + mi * 16 + lg * 4 + r;
        if (row >= ag.M) continue;
#pragma unroll
        for (int ni = 0; ni < 4; ++ni) {
          const int col = n0 + wc * 64 + ni * 16 + lr;
          if constexpr (MODE == 4) {
            u16* pb = (tapz < 5) ? ag.outH : ag.outQ;
            const int tl = (tapz < 5) ? tapz : tapz - 5;
            pb[(size_t)tl * PSZ + (size_t)row * CHN + col] = f2b(acc[mi][ni][r]);
          } else {
            const float v = acc[mi][ni][r] + ag.bias[col];
            if constexpr (MODE == 1) {
              const size_t idx = (size_t)row * CC + col;
              ag.outF[idx] = v + ag.res[idx];
            } else {
              const int b = row / PIX, p = row - b * PIX;
              const size_t idx = (size_t)(b * NN + p) * CC + col;
              ag.outF[idx] = v + ag.res[idx];
            }
          }
        }
      }
    }
  }
}

// ---------------- conv1 reduce: f1 = gelu(sum of 9 bf16 partials + bias) -> bf16 ----
__global__ __launch_bounds__(256) void gelu_reduce_kernel(
    const u16* __restrict__ pA, const u16* __restrict__ pB,
    const float* __restrict__ bias, u16* __restrict__ f1) {
  const size_t i4 = ((size_t)blockIdx.x * 256 + threadIdx.x) * 4;
  const int col = (int)(i4 & 255);
  float s0 = 0.f, s1 = 0.f, s2 = 0.f, s3 = 0.f;
#pragma unroll
  for (int t = 0; t < 5; ++t) {
    ushort4 u = *(const ushort4*)(pA + (size_t)t * PSZ + i4);
    s0 += b2f(u.x); s1 += b2f(u.y); s2 += b2f(u.z); s3 += b2f(u.w);
  }
#pragma unroll
  for (int t = 0; t < 4; ++t) {
    ushort4 u = *(const ushort4*)(pB + (size_t)t * PSZ + i4);
    s0 += b2f(u.x); s1 += b2f(u.y); s2 += b2f(u.z); s3 += b2f(u.w);
  }
  const float4 b4 = *(const float4*)(bias + col);
  ushort4 st = make_ushort4(f2b(gelu_tanh(s0 + b4.x)), f2b(gelu_tanh(s1 + b4.y)),
                            f2b(gelu_tanh(s2 + b4.z)), f2b(gelu_tanh(s3 + b4.w)));
  *(ushort4*)(f1 + i4) = st;
}

// ---------------- fused flash attention v3: 8 waves, QBLK=128, LDS-shared K/V -------
// K/V staged once per block (double-buffered, gld_lds, source-side XOR by row&7),
// counted vmcnt + raw barriers. Swapped QK^T + in-lane softmax + defer-max kept.
__global__ __launch_bounds__(512) void attn_kernel(
    const u16* __restrict__ q, const u16* __restrict__ k,
    const u16* __restrict__ vt, u16* __restrict__ o) {
  // LDS: K bufs [0,8192), V bufs [8192,16384), P per-wave [16384,24576)  (u16 units)
  __shared__ u16 SH2[24576];
  const int tid = threadIdx.x;
  const int w = tid >> 6, l = tid & 63;
  const int lr = l & 15, lg = l >> 4;
  const int lg4 = lg * 4;
  const int bid = blockIdx.x;
  const int xcd = bid & 7, gg = bid >> 3;
  const int bh = (gg / 5) * 8 + xcd;   // all 5 q-tiles of a head share an XCD
  const int qt = gg % 5;
  const int b = bh >> 4, h = bh & 15;

  const u16* qp = q + (size_t)bh * NN * DD;
  const u16* kp = k + (size_t)bh * NN * DD;
  const u16* vp = vt + (size_t)bh * DD * VROW;

  const int qrow = qt * 128 + w * 16 + lr;
  const int qrc = qrow < NN ? qrow : NN - 1;
  const bf16x8 qf0 = ldfrag(qp + (size_t)qrc * DD + lg * 8);
  const bf16x8 qf1 = ldfrag(qp + (size_t)qrc * DD + 32 + lg * 8);

  // staging geometry: thread t covers row t>>3, 16B chunk t&7 (linear LDS dest);
  // source chunk pre-XORed by row&7 so reads can XOR-deswizzle (T2 both-sides).
  const int srow = l >> 3;                       // + w*8
  const int schk = (l & 7) ^ (srow & 7);         // source-side XOR
  auto stage = [&](int buf, int kt) {
    const int kb = kt * 64;
    gld_lds16(kp + (size_t)(kb + w * 8 + srow) * DD + schk * 8,
              &SH2[buf * 4096 + w * 512]);
    gld_lds16(vp + (size_t)(w * 8 + srow) * VROW + kb + schk * 8,
              &SH2[8192 + buf * 4096 + w * 512]);
  };

  f32x4 oa[4] = {};
  float mrow = -1e30f;
  float lsum = 0.f;
  u16* pw = &SH2[16384 + w * 1024];
  const int x7 = lr & 7;        // K/V read deswizzle
  const int x3 = lr & 3;        // P read/write deswizzle (64B rows)

  stage(0, 0);
  stage(1, 1);

  for (int kt = 0; kt < 10; ++kt) {
    if (kt <= 7) { asm volatile("s_waitcnt vmcnt(2)" ::: "memory"); }
    else         { asm volatile("s_waitcnt vmcnt(0)" ::: "memory"); }
    __builtin_amdgcn_s_barrier();
    const u16* KB = &SH2[(kt & 1) * 4096];
    const u16* VB = &SH2[8192 + (kt & 1) * 4096];
    const int kb = kt * 64;

    f32x4 s[4] = {};
#pragma unroll
    for (int g = 0; g < 4; ++g) {
      const int row = g * 16 + lr;
      const bf16x8 a0 = ldfrag(&KB[row * 64 + ((lg ^ x7) * 8)]);
      const bf16x8 a1 = ldfrag(&KB[row * 64 + (((4 + lg) ^ x7) * 8)]);
      s[g] = mfma16(a0, qf0, s[g]);   // swapped: scores^T, col = q-row = lr
      s[g] = mfma16(a1, qf1, s[g]);
    }
    float t[16];
    const bool last = (kt == 9);
#pragma unroll
    for (int g = 0; g < 4; ++g)
#pragma unroll
      for (int r = 0; r < 4; ++r) {
        const int key = kb + g * 16 + lg4 + r;
        t[g * 4 + r] = (!last || key < NN) ? s[g][r] : -3e38f;
      }
    float pmax = t[0];
#pragma unroll
    for (int i = 1; i < 16; ++i) pmax = fmaxf(pmax, t[i]);
    pmax = fmaxf(pmax, __shfl_xor(pmax, 16));
    pmax = fmaxf(pmax, __shfl_xor(pmax, 32));
    if (!__all(pmax <= mrow + 8.f)) {   // defer-max
      const float mn = fmaxf(mrow, pmax);
      const float corr = exp2f(mrow - mn);
      mrow = mn;
      lsum *= corr;
      float bc[4];
#pragma unroll
      for (int r = 0; r < 4; ++r) bc[r] = __shfl(corr, (l & 48) | (lg4 + r));
#pragma unroll
      for (int g = 0; g < 4; ++g)
#pragma unroll
        for (int r = 0; r < 4; ++r) oa[g][r] *= bc[r];
    }
    float ps[16];
    float rsum = 0.f;
#pragma unroll
    for (int i = 0; i < 16; ++i) { ps[i] = exp2f(t[i] - mrow); rsum += ps[i]; }
    rsum += __shfl_xor(rsum, 16);
    rsum += __shfl_xor(rsum, 32);
    lsum += rsum;
    // P -> LDS (keys for q-row lr), 64B rows, chunk XOR by q&3
#pragma unroll
    for (int g = 0; g < 4; ++g) {
      u32 w0, w1;
      asm("v_cvt_pk_bf16_f32 %0, %1, %2" : "=v"(w0) : "v"(ps[g * 4 + 0]), "v"(ps[g * 4 + 1]));
      asm("v_cvt_pk_bf16_f32 %0, %1, %2" : "=v"(w1) : "v"(ps[g * 4 + 2]), "v"(ps[g * 4 + 3]));
      const int lc = (g & 1) * 2 + (lg >> 1);              // logical 16B chunk in half
      const int off = (g >> 1) * 512 + lr * 32 + ((lc ^ x3) * 8) + (lg & 1) * 4;
      *(uint2*)(&pw[off]) = make_uint2(w0, w1);
    }
    asm volatile("s_waitcnt lgkmcnt(0)" ::: "memory");
    const bf16x8 paf = ldfrag(&pw[lr * 32 + ((lg ^ x3) * 8)]);
    const bf16x8 pbf = ldfrag(&pw[512 + lr * 32 + ((lg ^ x3) * 8)]);
#pragma unroll
    for (int dg = 0; dg < 4; ++dg) {
      const int row = dg * 16 + lr;
      const bf16x8 v0 = ldfrag(&VB[row * 64 + ((lg ^ x7) * 8)]);
      const bf16x8 v1 = ldfrag(&VB[row * 64 + (((4 + lg) ^ x7) * 8)]);
      oa[dg] = mfma16(paf, v0, oa[dg]);
      oa[dg] = mfma16(pbf, v1, oa[dg]);
    }
    asm volatile("s_waitcnt lgkmcnt(0)" ::: "memory");  // my LDS reads retired
    __builtin_amdgcn_s_barrier();                        // buffer safe to overwrite
    if (kt + 2 <= 9) stage(kt & 1, kt + 2);
  }

  const int nq = qt * 128 + w * 16 + lg4;
  float linv[4];
#pragma unroll
  for (int r = 0; r < 4; ++r) linv[r] = __shfl(lsum, (l & 48) | (lg4 + r));
#pragma unroll
  for (int r = 0; r < 4; ++r) {
    const int n = nq + r;
    if (n >= NN) continue;
    const float inv = 1.0f / linv[r];
#pragma unroll
    for (int g = 0; g < 4; ++g)
      o[(size_t)(b * NN + n) * CC + h * DD + g * 16 + lr] = f2b(oa[g][r] * inv);
  }
}

// =====================================================================================
extern "C" void kernel_launch(void* const* d_in, const int* in_sizes, int n_in,
                              void* d_out, int out_size, void* d_ws, size_t ws_size,
                              hipStream_t stream) {
  const float* x     = (const float*)d_in[0];
  const float* ln1_g = (const float*)d_in[1];
  const float* ln1_b = (const float*)d_in[2];
  const float* in_w  = (const float*)d_in[3];
  const float* in_b  = (const float*)d_in[4];
  const float* out_w = (const float*)d_in[5];
  const float* out_b = (const float*)d_in[6];
  const float* ln2_g = (const float*)d_in[7];
  const float* ln2_b = (const float*)d_in[8];
  const float* c1w   = (const float*)d_in[9];
  const float* c1b   = (const float*)d_in[10];
  const float* c2w   = (const float*)d_in[11];
  const float* c2b   = (const float*)d_in[12];
  float* out = (float*)d_out;

  char* ws = (char*)d_ws;
  size_t off = 0;
  auto alloc = [&](size_t bytes) {
    void* p = ws + off;
    off += (bytes + 255) & ~(size_t)255;
    return p;
  };
  u16* hb   = (u16*)alloc((size_t)BN * CC * 2);
  u16* wqkv = (u16*)alloc((size_t)3072 * 1024 * 2);
  u16* wout = (u16*)alloc((size_t)1024 * 1024 * 2);
  u16* w1t  = (u16*)alloc((size_t)256 * 9216 * 2);
  u16* w2t  = (u16*)alloc((size_t)1024 * 2304 * 2);
  u16* qb   = (u16*)alloc((size_t)256 * NN * DD * 2);
  u16* kb   = (u16*)alloc((size_t)256 * NN * DD * 2);
  u16* vtb  = (u16*)alloc((size_t)256 * DD * VROW * 2 + 16384);
  float* x2 = (float*)alloc((size_t)BN * CC * 4);
  u16* zpad = (u16*)alloc(256);
  u16* ob = hb;
  u16* yb = qb;
  u16* f1 = kb;
  u16* pA = hb;
  u16* pB = vtb;

  prep_kernel<<<1024, 256, 0, stream>>>(in_w, out_w, c1w, c2w, wqkv, wout, w1t, w2t, zpad);
  ln_kernel<0><<<BN, 256, 0, stream>>>(x, ln1_g, ln1_b, hb, nullptr);
  {
    GArgs a{hb, wqkv, in_b, nullptr, nullptr, nullptr, qb, kb, vtb, zpad, BN, CC};
    gemm_kernel<0><<<dim3(73, 24), 256, 0, stream>>>(a);
  }
  attn_kernel<<<1280, 512, 0, stream>>>(qb, kb, vtb, ob);
  {
    GArgs a{ob, wout, out_b, x, x2, nullptr, nullptr, nullptr, nullptr, zpad, BN, CC};
    gemm_kernel<1><<<dim3(73, 8), 256, 0, stream>>>(a);
  }
  ln_kernel<1><<<BN, 256, 0, stream>>>(x2, ln2_g, ln2_b, yb, out);
  {
    GArgs a{yb, w1t, c1b, nullptr, nullptr, pA, pB, nullptr, nullptr, zpad, 9216, 9216};
    gemm_kernel<4><<<dim3(72, 2, 9), 256, 0, stream>>>(a);
  }
  gelu_reduce_kernel<<<2304, 256, 0, stream>>>(pA, pB, c1b, f1);
  {
    GArgs a{f1, w2t, c2b, x2, out, nullptr, nullptr, nullptr, nullptr, zpad, 9216, 2304};
    gemm_kernel<3><<<dim3(72, 8), 256, 0, stream>>>(a);
  }
}